// Round 1
// baseline (745.504 us; speedup 1.0000x reference)
//
#include <hip/hip_runtime.h>

typedef __bf16 bf16x8 __attribute__((ext_vector_type(8)));
typedef float floatx4 __attribute__((ext_vector_type(4)));

#define MFMA(a, b, c) __builtin_amdgcn_mfma_f32_16x16x32_bf16((a), (b), (c), 0, 0, 0)

__device__ __forceinline__ unsigned short f2bf(float x) {
  union { float f; unsigned u; } v; v.f = x;
  unsigned r = v.u + 0x7FFFu + ((v.u >> 16) & 1u);  // RNE; inputs finite
  return (unsigned short)(r >> 16);
}

constexpr int LD = 72;  // padded row stride (bf16 elems): 144 B, 16B-aligned, conflict-free frag reads

__global__ __launch_bounds__(256, 4)
void attn_fwd(const float* __restrict__ Q, const float* __restrict__ K,
              const float* __restrict__ V, float* __restrict__ outQV,
              float* __restrict__ outA)
{
  __shared__ __align__(16) unsigned short Qs[64 * LD];
  __shared__ __align__(16) unsigned short Ks[64 * LD];
  __shared__ __align__(16) unsigned short Vts[64 * LD];  // Vts[d][m]
  __shared__ __align__(16) unsigned short As[64 * LD];   // P staging, wave-private rows

  const int tid = threadIdx.x;
  const int w  = tid >> 6;   // wave 0..3 -> q rows [16w,16w+16)
  const int l  = tid & 63;
  const int c  = l & 15;
  const int q4 = l >> 4;

  const int bx = blockIdx.x;
  const int qt = bx & 31;
  const int h  = (bx >> 5) & 7;
  const int b  = bx >> 8;
  const int q0 = qt * 64;

  const float scale = 0.125f * 1.44269504088896340736f;  // 1/sqrt(64) * log2(e)

  const size_t base = (size_t)b * (2048 * 512) + (size_t)h * 64;  // + n*512 + d
  const float* Qb = Q + base + (size_t)q0 * 512;
  const float* Kb = K + base;
  const float* Vb = V + base;

  const int r0 = tid >> 4;   // loader row
  const int c4 = tid & 15;   // loader float4 column

  // ---- load Q tile (scaled, bf16) ----
  #pragma unroll
  for (int g = 0; g < 4; ++g) {
    int r = r0 + 16 * g;
    float4 qv = *(const float4*)(Qb + (size_t)r * 512 + c4 * 4);
    unsigned short* dst = &Qs[r * LD + c4 * 4];
    dst[0] = f2bf(qv.x * scale); dst[1] = f2bf(qv.y * scale);
    dst[2] = f2bf(qv.z * scale); dst[3] = f2bf(qv.w * scale);
  }

  // ---- pass 1: per-row sum of exp2(S) (no max-sub; |s2| < ~9, fp32-safe) ----
  float lsum[4] = {0.f, 0.f, 0.f, 0.f};
  for (int mc = 0; mc < 2048; mc += 64) {
    __syncthreads();
    #pragma unroll
    for (int g = 0; g < 4; ++g) {
      int r = r0 + 16 * g;
      float4 kv = *(const float4*)(Kb + (size_t)(mc + r) * 512 + c4 * 4);
      unsigned short* dst = &Ks[r * LD + c4 * 4];
      dst[0] = f2bf(kv.x); dst[1] = f2bf(kv.y);
      dst[2] = f2bf(kv.z); dst[3] = f2bf(kv.w);
    }
    __syncthreads();
    bf16x8 aQ0 = *(const bf16x8*)&Qs[(16 * w + c) * LD + q4 * 8];
    bf16x8 aQ1 = *(const bf16x8*)&Qs[(16 * w + c) * LD + 32 + q4 * 8];
    #pragma unroll
    for (int t = 0; t < 4; ++t) {
      bf16x8 bK0 = *(const bf16x8*)&Ks[(t * 16 + c) * LD + q4 * 8];
      bf16x8 bK1 = *(const bf16x8*)&Ks[(t * 16 + c) * LD + 32 + q4 * 8];
      floatx4 acc = {0.f, 0.f, 0.f, 0.f};
      acc = MFMA(aQ0, bK0, acc);
      acc = MFMA(aQ1, bK1, acc);
      #pragma unroll
      for (int i = 0; i < 4; ++i) lsum[i] += exp2f(acc[i]);
    }
  }
  // sum is linear: one cross-lane reduction at the end (lanes c=0..15 share rows)
  float rcp[4];
  #pragma unroll
  for (int i = 0; i < 4; ++i) {
    float v = lsum[i];
    v += __shfl_xor(v, 1);
    v += __shfl_xor(v, 2);
    v += __shfl_xor(v, 4);
    v += __shfl_xor(v, 8);
    rcp[i] = 1.0f / v;   // once per block, full-precision div is fine
  }

  // ---- pass 2: recompute S, write A, accumulate O = A*V ----
  floatx4 Oacc[4];
  #pragma unroll
  for (int t = 0; t < 4; ++t) Oacc[t] = (floatx4){0.f, 0.f, 0.f, 0.f};

  float* aBase = outA + (((size_t)(b * 8 + h) * 2048 + q0 + 16 * w + q4 * 4) * 2048);

  for (int mc = 0; mc < 2048; mc += 64) {
    __syncthreads();  // prev-iter PV reads of Vts done before overwrite
    #pragma unroll
    for (int g = 0; g < 4; ++g) {
      int r = r0 + 16 * g;
      float4 kv = *(const float4*)(Kb + (size_t)(mc + r) * 512 + c4 * 4);
      unsigned short* dst = &Ks[r * LD + c4 * 4];
      dst[0] = f2bf(kv.x); dst[1] = f2bf(kv.y);
      dst[2] = f2bf(kv.z); dst[3] = f2bf(kv.w);
    }
    #pragma unroll
    for (int g = 0; g < 4; ++g) {
      int m = r0 + 16 * g;
      float4 vv = *(const float4*)(Vb + (size_t)(mc + m) * 512 + c4 * 4);
      Vts[(c4 * 4 + 0) * LD + m] = f2bf(vv.x);
      Vts[(c4 * 4 + 1) * LD + m] = f2bf(vv.y);
      Vts[(c4 * 4 + 2) * LD + m] = f2bf(vv.z);
      Vts[(c4 * 4 + 3) * LD + m] = f2bf(vv.w);
    }
    __syncthreads();
    bf16x8 aQ0 = *(const bf16x8*)&Qs[(16 * w + c) * LD + q4 * 8];
    bf16x8 aQ1 = *(const bf16x8*)&Qs[(16 * w + c) * LD + 32 + q4 * 8];
    #pragma unroll
    for (int t = 0; t < 4; ++t) {
      bf16x8 bK0 = *(const bf16x8*)&Ks[(t * 16 + c) * LD + q4 * 8];
      bf16x8 bK1 = *(const bf16x8*)&Ks[(t * 16 + c) * LD + 32 + q4 * 8];
      floatx4 acc = {0.f, 0.f, 0.f, 0.f};
      acc = MFMA(aQ0, bK0, acc);
      acc = MFMA(aQ1, bK1, acc);
      #pragma unroll
      for (int i = 0; i < 4; ++i) {
        float a = exp2f(acc[i]) * rcp[i];
        aBase[(size_t)i * 2048 + mc + t * 16 + c] = a;                 // coalesced 64B segs/row
        As[(16 * w + q4 * 4 + i) * LD + t * 16 + c] = f2bf(a);         // wave-private rows
      }
    }
    // PV: A-operand = P rows (own wave's rows only -> same-wave LDS RAW, no barrier needed)
    bf16x8 aP0 = *(const bf16x8*)&As[(16 * w + c) * LD + q4 * 8];
    bf16x8 aP1 = *(const bf16x8*)&As[(16 * w + c) * LD + 32 + q4 * 8];
    #pragma unroll
    for (int t = 0; t < 4; ++t) {
      bf16x8 bV0 = *(const bf16x8*)&Vts[(t * 16 + c) * LD + q4 * 8];
      bf16x8 bV1 = *(const bf16x8*)&Vts[(t * 16 + c) * LD + 32 + q4 * 8];
      Oacc[t] = MFMA(aP0, bV0, Oacc[t]);
      Oacc[t] = MFMA(aP1, bV1, Oacc[t]);
    }
  }

  // ---- write queried_values [B,N,H,D] ----
  #pragma unroll
  for (int t = 0; t < 4; ++t) {
    #pragma unroll
    for (int i = 0; i < 4; ++i) {
      outQV[base + (size_t)(q0 + 16 * w + q4 * 4 + i) * 512 + t * 16 + c] = Oacc[t][i];
    }
  }
}

extern "C" void kernel_launch(void* const* d_in, const int* in_sizes, int n_in,
                              void* d_out, int out_size, void* d_ws, size_t ws_size,
                              hipStream_t stream)
{
  const float* Q = (const float*)d_in[0];
  const float* K = (const float*)d_in[1];
  const float* V = (const float*)d_in[2];
  float* outQV = (float*)d_out;                 // [4,2048,8,64] = 4194304 floats
  float* outA  = (float*)d_out + 4194304;       // [4,8,2048,2048]
  attn_fwd<<<dim3(1024), dim3(256), 0, stream>>>(Q, K, V, outQV, outA);
}